// Round 8
// baseline (627.692 us; speedup 1.0000x reference)
//
#include <hip/hip_runtime.h>
#include <math.h>

#define H 128
#define OUTD 40
#define BN_EPS 1e-5f
#define NEG_SLOPE 0.01f

typedef __attribute__((ext_vector_type(8))) short bh8;
typedef __attribute__((ext_vector_type(4))) float f4;
typedef unsigned short u16;

__device__ __forceinline__ float4 ld4(const float* p) {
    return *reinterpret_cast<const float4*>(p);
}
__device__ __forceinline__ u16 f2bf(float f) {
    unsigned int u = __float_as_uint(f);
    u += 0x7fffu + ((u >> 16) & 1u);          // RNE
    return (u16)(u >> 16);
}
__device__ __forceinline__ float bflo(unsigned d) { return __uint_as_float(d << 16); }
__device__ __forceinline__ float bfhi(unsigned d) { return __uint_as_float(d & 0xffff0000u); }
__device__ __forceinline__ unsigned pk(float a, float b) {
    return (unsigned)f2bf(a) | ((unsigned)f2bf(b) << 16);
}
// LDS XOR swizzle for 256B rows (bf16 x 128)
__device__ __forceinline__ int swz(int row, int byteInRow) {
    return row * 256 + (byteInRow ^ ((row & 7) << 4));
}

// ================= x -> bf16 =================
__global__ __launch_bounds__(256) void k_xbf(
    const float* __restrict__ x, u16* __restrict__ xb, int total8)
{
    int i = blockIdx.x * 256 + threadIdx.x;
    if (i >= total8) return;
    float4 a = ld4(x + (size_t)i * 8);
    float4 b = ld4(x + (size_t)i * 8 + 4);
    uint4 o;
    o.x = pk(a.x, a.y); o.y = pk(a.z, a.w);
    o.z = pk(b.x, b.y); o.w = pk(b.z, b.w);
    *reinterpret_cast<uint4*>(xb + (size_t)i * 8) = o;
}

// ================= weight prep: WT[c][k] = bf16(W[k][c]) =================
__global__ __launch_bounds__(256) void k_prep(
    const float* __restrict__ w1, const float* __restrict__ w2,
    const float* __restrict__ wl, const float* __restrict__ wr,
    u16* __restrict__ wt1, u16* __restrict__ wt2,
    u16* __restrict__ wtl, u16* __restrict__ wtr)
{
    int id = blockIdx.x * 256 + threadIdx.x;
    int sel = id >> 14;
    int o = id & 16383;
    int c = o >> 7, k = o & 127;
    const float* w = (sel == 0) ? w1 : (sel == 1) ? w2 : (sel == 2) ? wl : wr;
    u16* wt = (sel == 0) ? wt1 : (sel == 1) ? wt2 : (sel == 2) ? wtl : wtr;
    wt[o] = f2bf(w[k * H + c]);
}

// ================= CSR build =================
__global__ __launch_bounds__(256) void k_hist(
    const int* __restrict__ dst, int* __restrict__ deg, int E)
{
    int e = blockIdx.x * 256 + threadIdx.x;
    if (e < E) atomicAdd(&deg[dst[e]], 1);
}

__global__ __launch_bounds__(256) void k_scan1(
    const int* __restrict__ deg, int* __restrict__ cursor, int* __restrict__ bsum, int n)
{
    __shared__ int sums[256];
    const int tid = threadIdx.x;
    const int idx = blockIdx.x * 1024 + tid * 4;
    int4 v = {0, 0, 0, 0};
    if (idx + 3 < n) v = *reinterpret_cast<const int4*>(deg + idx);
    else {
        if (idx + 0 < n) v.x = deg[idx + 0];
        if (idx + 1 < n) v.y = deg[idx + 1];
        if (idx + 2 < n) v.z = deg[idx + 2];
        if (idx + 3 < n) v.w = deg[idx + 3];
    }
    int t = v.x + v.y + v.z + v.w;
    sums[tid] = t;
    __syncthreads();
    for (int off = 1; off < 256; off <<= 1) {
        int other = (tid >= off) ? sums[tid - off] : 0;
        __syncthreads();
        sums[tid] += other;
        __syncthreads();
    }
    int incl = sums[tid];
    int excl = incl - t;
    if (tid == 255) bsum[blockIdx.x] = incl;
    int c0 = excl, c1 = c0 + v.x, c2 = c1 + v.y, c3 = c2 + v.z;
    if (idx + 3 < n) {
        int4 o = {c0, c1, c2, c3};
        *reinterpret_cast<int4*>(cursor + idx) = o;
    } else {
        if (idx + 0 < n) cursor[idx + 0] = c0;
        if (idx + 1 < n) cursor[idx + 1] = c1;
        if (idx + 2 < n) cursor[idx + 2] = c2;
        if (idx + 3 < n) cursor[idx + 3] = c3;
    }
}

__global__ void k_scan2(int* __restrict__ bsum, int nb)
{
    __shared__ int s[1024];
    const int tid = threadIdx.x;
    for (int i = tid; i < nb; i += blockDim.x) s[i] = bsum[i];
    __syncthreads();
    if (tid == 0) {
        int acc = 0;
        for (int i = 0; i < nb; i++) { int t = s[i]; s[i] = acc; acc += t; }
    }
    __syncthreads();
    for (int i = tid; i < nb; i += blockDim.x) bsum[i] = s[i];
}

// scan3 + dinv fused
__global__ __launch_bounds__(256) void k_scan3(
    int* __restrict__ cursor, const int* __restrict__ bsum,
    const int* __restrict__ deg, float* __restrict__ dinv, int n)
{
    int i = blockIdx.x * 256 + threadIdx.x;
    if (i < n) {
        cursor[i] += bsum[i >> 10];
        dinv[i] = rsqrtf((float)deg[i] + 1.0f);
    }
}

// ranged fill: only edges whose dst falls in [lo,hi) — keeps the csr write
// window (~1.6MB) resident in each XCD L2 so stores coalesce before writeback
__global__ __launch_bounds__(256) void k_fill_range(
    const int* __restrict__ src, const int* __restrict__ dst,
    int* __restrict__ cursor, int* __restrict__ csr, int E, int lo, int hi)
{
    int e = blockIdx.x * 256 + threadIdx.x;
    if (e >= E) return;
    int d = dst[e];
    if (d < lo || d >= hi) return;
    int pos = atomicAdd(&cursor[d], 1);
    csr[pos] = src[e];
}

// ================= fused layer-1: gather-sum + GEMM1 =================
// Block = 64 rows. Phase A: 4 waves gather 16 rows each (4 rows at a time,
// 16 lanes x 8 bf16 per row) directly into swizzled sA. Phase B: MFMA.
__global__ __launch_bounds__(256) void k_agg1lin1(
    const u16* __restrict__ xb, const int* __restrict__ csr,
    const int* __restrict__ cursor, const int* __restrict__ deg,
    const u16* __restrict__ WT, const float* __restrict__ bias,
    u16* __restrict__ out, int n)
{
    __shared__ u16 sA[64 * 128];
    __shared__ u16 sB[128 * 128];
    const int tid = threadIdx.x;
    const int rb = blockIdx.x * 64;
#pragma unroll
    for (int j = 0; j < 8; j++) {               // stage W^T
        int f = j * 256 + tid;
        int r = f >> 4, kb = f & 15;
        uint4 v = *reinterpret_cast<const uint4*>(WT + r * H + kb * 8);
        *reinterpret_cast<uint4*>((char*)sB + swz(r, kb * 16)) = v;
    }
    const int wv = tid >> 6, lane = tid & 63, g = lane & 15, rq = lane >> 4;
#pragma unroll
    for (int t = 0; t < 4; t++) {
        int rl = wv * 16 + t * 4 + rq;
        int row = rb + rl;
        float acc[8] = {0.f, 0.f, 0.f, 0.f, 0.f, 0.f, 0.f, 0.f};
        if (row < n) {
            int end = cursor[row];
            int i = end - deg[row];
            for (; i + 2 <= end; i += 2) {
                int s0 = csr[i], s1 = csr[i + 1];
                uint4 a = *reinterpret_cast<const uint4*>(xb + (size_t)s0 * H + g * 8);
                uint4 b = *reinterpret_cast<const uint4*>(xb + (size_t)s1 * H + g * 8);
                acc[0] += bflo(a.x) + bflo(b.x); acc[1] += bfhi(a.x) + bfhi(b.x);
                acc[2] += bflo(a.y) + bflo(b.y); acc[3] += bfhi(a.y) + bfhi(b.y);
                acc[4] += bflo(a.z) + bflo(b.z); acc[5] += bfhi(a.z) + bfhi(b.z);
                acc[6] += bflo(a.w) + bflo(b.w); acc[7] += bfhi(a.w) + bfhi(b.w);
            }
            for (; i < end; i++) {
                int s = csr[i];
                uint4 a = *reinterpret_cast<const uint4*>(xb + (size_t)s * H + g * 8);
                acc[0] += bflo(a.x); acc[1] += bfhi(a.x);
                acc[2] += bflo(a.y); acc[3] += bfhi(a.y);
                acc[4] += bflo(a.z); acc[5] += bfhi(a.z);
                acc[6] += bflo(a.w); acc[7] += bfhi(a.w);
            }
        }
        uint4 o;
        o.x = pk(acc[0], acc[1]); o.y = pk(acc[2], acc[3]);
        o.z = pk(acc[4], acc[5]); o.w = pk(acc[6], acc[7]);
        *reinterpret_cast<uint4*>((char*)sA + swz(rl, g * 16)) = o;
    }
    __syncthreads();
    const int w = tid >> 6, l15 = tid & 15, grp = (tid & 63) >> 4;
    f4 acc[8] = {};
#pragma unroll
    for (int kc = 0; kc < 4; kc++) {
        bh8 af = *reinterpret_cast<const bh8*>((char*)sA + swz(w * 16 + l15, kc * 64 + grp * 16));
#pragma unroll
        for (int nf = 0; nf < 8; nf++) {
            bh8 bv = *reinterpret_cast<const bh8*>((char*)sB + swz(nf * 16 + l15, kc * 64 + grp * 16));
            acc[nf] = __builtin_amdgcn_mfma_f32_16x16x32_bf16(af, bv, acc[nf], 0, 0, 0);
        }
    }
#pragma unroll
    for (int nf = 0; nf < 8; nf++) {
        int col = nf * 16 + l15;
        float bc = bias[col];
#pragma unroll
        for (int j = 0; j < 4; j++) {
            int row = rb + w * 16 + grp * 4 + j;
            if (row < n) {
                float u = acc[nf][j] + bc;
                u = u > 0.f ? u : NEG_SLOPE * u;
                out[(size_t)row * H + col] = f2bf(u);
            }
        }
    }
}

// GEMM2: u = A @ W2 + b2; L2-normalize rows; write bf16 h; BN1 stats
__global__ __launch_bounds__(256) void k_gemm_lin2norm(
    const u16* __restrict__ A, const u16* __restrict__ WT,
    const float* __restrict__ bias, u16* __restrict__ out,
    float* __restrict__ gsum, float* __restrict__ gsumsq, int n)
{
    __shared__ u16 sA[64 * 128];
    __shared__ u16 sB[128 * 128];
    __shared__ float cs[128], css[128];
    const int tid = threadIdx.x;
    const int rb = blockIdx.x * 64;
    if (tid < 128) { cs[tid] = 0.f; css[tid] = 0.f; }
#pragma unroll
    for (int j = 0; j < 4; j++) {
        int f = j * 256 + tid;
        int r = f >> 4, g = f & 15;
        int row = rb + r;
        uint4 v = {0, 0, 0, 0};
        if (row < n) v = *reinterpret_cast<const uint4*>(A + (size_t)row * H + g * 8);
        *reinterpret_cast<uint4*>((char*)sA + swz(r, g * 16)) = v;
    }
#pragma unroll
    for (int j = 0; j < 8; j++) {
        int f = j * 256 + tid;
        int r = f >> 4, kb = f & 15;
        uint4 v = *reinterpret_cast<const uint4*>(WT + r * H + kb * 8);
        *reinterpret_cast<uint4*>((char*)sB + swz(r, kb * 16)) = v;
    }
    __syncthreads();
    const int w = tid >> 6, l15 = tid & 15, grp = (tid & 63) >> 4;
    f4 acc[8] = {};
#pragma unroll
    for (int kc = 0; kc < 4; kc++) {
        bh8 af = *reinterpret_cast<const bh8*>((char*)sA + swz(w * 16 + l15, kc * 64 + grp * 16));
#pragma unroll
        for (int nf = 0; nf < 8; nf++) {
            bh8 bv = *reinterpret_cast<const bh8*>((char*)sB + swz(nf * 16 + l15, kc * 64 + grp * 16));
            acc[nf] = __builtin_amdgcn_mfma_f32_16x16x32_bf16(af, bv, acc[nf], 0, 0, 0);
        }
    }
#pragma unroll
    for (int nf = 0; nf < 8; nf++) {
        float bc = bias[nf * 16 + l15];
#pragma unroll
        for (int j = 0; j < 4; j++) acc[nf][j] += bc;
    }
    float inv[4];
#pragma unroll
    for (int j = 0; j < 4; j++) {
        float ss = 0.f;
#pragma unroll
        for (int nf = 0; nf < 8; nf++) ss += acc[nf][j] * acc[nf][j];
        ss += __shfl_xor(ss, 1, 64); ss += __shfl_xor(ss, 2, 64);
        ss += __shfl_xor(ss, 4, 64); ss += __shfl_xor(ss, 8, 64);
        inv[j] = 1.0f / fmaxf(sqrtf(ss), 1e-12f);
    }
#pragma unroll
    for (int nf = 0; nf < 8; nf++) {
        int col = nf * 16 + l15;
        float s = 0.f, q = 0.f;
#pragma unroll
        for (int j = 0; j < 4; j++) {
            int row = rb + w * 16 + grp * 4 + j;
            float u = acc[nf][j] * inv[j];
            if (row < n) {
                out[(size_t)row * H + col] = f2bf(u);
                s += u; q += u * u;
            }
        }
        s += __shfl_xor(s, 16, 64); s += __shfl_xor(s, 32, 64);
        q += __shfl_xor(q, 16, 64); q += __shfl_xor(q, 32, 64);
        if (grp == 0) { atomicAdd(&cs[col], s); atomicAdd(&css[col], q); }
    }
    __syncthreads();
    if (tid < 128) { atomicAdd(gsum + tid, cs[tid]); atomicAdd(gsumsq + tid, css[tid]); }
}

// ================= fused layer-2: gather-mean + SAGE =================
// Phase A: gather mean(relu(affine1(h[src]))) into sA; MFMA @ Wl.
// Phase B: restage sA = relu(affine1(h[row])) row-local, sB = WrT; MFMA.
__global__ __launch_bounds__(256) void k_agg2sage(
    const u16* __restrict__ Hb, const int* __restrict__ csr,
    const int* __restrict__ cursor, const int* __restrict__ deg,
    const float* __restrict__ scale1, const float* __restrict__ shift1,
    const u16* __restrict__ WlT, const u16* __restrict__ WrT,
    const float* __restrict__ bl, u16* __restrict__ out,
    float* __restrict__ gsum, float* __restrict__ gsumsq, int n)
{
    __shared__ u16 sA[64 * 128];
    __shared__ u16 sB[128 * 128];
    __shared__ float cs[128], css[128];
    const int tid = threadIdx.x;
    const int rb = blockIdx.x * 64;
    if (tid < 128) { cs[tid] = 0.f; css[tid] = 0.f; }
#pragma unroll
    for (int j = 0; j < 8; j++) {               // stage WlT
        int f = j * 256 + tid;
        int r = f >> 4, kb = f & 15;
        uint4 v = *reinterpret_cast<const uint4*>(WlT + r * H + kb * 8);
        *reinterpret_cast<uint4*>((char*)sB + swz(r, kb * 16)) = v;
    }
    const int wv = tid >> 6, lane = tid & 63, g = lane & 15, rq = lane >> 4;
    float4 sc0 = ld4(scale1 + g * 8), sc1 = ld4(scale1 + g * 8 + 4);
    float4 sh0 = ld4(shift1 + g * 8), sh1 = ld4(shift1 + g * 8 + 4);
#pragma unroll
    for (int t = 0; t < 4; t++) {
        int rl = wv * 16 + t * 4 + rq;
        int row = rb + rl;
        float acc[8] = {0.f, 0.f, 0.f, 0.f, 0.f, 0.f, 0.f, 0.f};
        float idv = 0.f;
        if (row < n) {
            int end = cursor[row];
            int dg = deg[row];
            int i = end - dg;
            for (; i + 2 <= end; i += 2) {
                int s0 = csr[i], s1 = csr[i + 1];
                uint4 a = *reinterpret_cast<const uint4*>(Hb + (size_t)s0 * H + g * 8);
                uint4 b = *reinterpret_cast<const uint4*>(Hb + (size_t)s1 * H + g * 8);
                acc[0] += fmaxf(bflo(a.x) * sc0.x + sh0.x, 0.f) + fmaxf(bflo(b.x) * sc0.x + sh0.x, 0.f);
                acc[1] += fmaxf(bfhi(a.x) * sc0.y + sh0.y, 0.f) + fmaxf(bfhi(b.x) * sc0.y + sh0.y, 0.f);
                acc[2] += fmaxf(bflo(a.y) * sc0.z + sh0.z, 0.f) + fmaxf(bflo(b.y) * sc0.z + sh0.z, 0.f);
                acc[3] += fmaxf(bfhi(a.y) * sc0.w + sh0.w, 0.f) + fmaxf(bfhi(b.y) * sc0.w + sh0.w, 0.f);
                acc[4] += fmaxf(bflo(a.z) * sc1.x + sh1.x, 0.f) + fmaxf(bflo(b.z) * sc1.x + sh1.x, 0.f);
                acc[5] += fmaxf(bfhi(a.z) * sc1.y + sh1.y, 0.f) + fmaxf(bfhi(b.z) * sc1.y + sh1.y, 0.f);
                acc[6] += fmaxf(bflo(a.w) * sc1.z + sh1.z, 0.f) + fmaxf(bflo(b.w) * sc1.z + sh1.z, 0.f);
                acc[7] += fmaxf(bfhi(a.w) * sc1.w + sh1.w, 0.f) + fmaxf(bfhi(b.w) * sc1.w + sh1.w, 0.f);
            }
            for (; i < end; i++) {
                int s = csr[i];
                uint4 a = *reinterpret_cast<const uint4*>(Hb + (size_t)s * H + g * 8);
                acc[0] += fmaxf(bflo(a.x) * sc0.x + sh0.x, 0.f);
                acc[1] += fmaxf(bfhi(a.x) * sc0.y + sh0.y, 0.f);
                acc[2] += fmaxf(bflo(a.y) * sc0.z + sh0.z, 0.f);
                acc[3] += fmaxf(bfhi(a.y) * sc0.w + sh0.w, 0.f);
                acc[4] += fmaxf(bflo(a.z) * sc1.x + sh1.x, 0.f);
                acc[5] += fmaxf(bfhi(a.z) * sc1.y + sh1.y, 0.f);
                acc[6] += fmaxf(bflo(a.w) * sc1.z + sh1.z, 0.f);
                acc[7] += fmaxf(bfhi(a.w) * sc1.w + sh1.w, 0.f);
            }
            idv = 1.0f / fmaxf((float)dg, 1.0f);
        }
        uint4 o;
        o.x = pk(acc[0] * idv, acc[1] * idv); o.y = pk(acc[2] * idv, acc[3] * idv);
        o.z = pk(acc[4] * idv, acc[5] * idv); o.w = pk(acc[6] * idv, acc[7] * idv);
        *reinterpret_cast<uint4*>((char*)sA + swz(rl, g * 16)) = o;
    }
    __syncthreads();
    const int w = tid >> 6, l15 = tid & 15, grp = (tid & 63) >> 4;
    f4 acc[8] = {};
#pragma unroll
    for (int kc = 0; kc < 4; kc++) {
        bh8 af = *reinterpret_cast<const bh8*>((char*)sA + swz(w * 16 + l15, kc * 64 + grp * 16));
#pragma unroll
        for (int nf = 0; nf < 8; nf++) {
            bh8 bv = *reinterpret_cast<const bh8*>((char*)sB + swz(nf * 16 + l15, kc * 64 + grp * 16));
            acc[nf] = __builtin_amdgcn_mfma_f32_16x16x32_bf16(af, bv, acc[nf], 0, 0, 0);
        }
    }
    __syncthreads();   // all pass-1 reads done before restage

    // ---- pass 2: relu(affine1(h[row])) @ Wr ----
#pragma unroll
    for (int j = 0; j < 4; j++) {
        int f = j * 256 + tid;
        int r = f >> 4, gg = f & 15;
        int row = rb + r;
        uint4 o = {0, 0, 0, 0};
        if (row < n) {
            uint4 a = *reinterpret_cast<const uint4*>(Hb + (size_t)row * H + gg * 8);
            float4 c0 = ld4(scale1 + gg * 8), c1 = ld4(scale1 + gg * 8 + 4);
            float4 h0 = ld4(shift1 + gg * 8), h1 = ld4(shift1 + gg * 8 + 4);
            float e0 = fmaxf(bflo(a.x) * c0.x + h0.x, 0.f);
            float e1 = fmaxf(bfhi(a.x) * c0.y + h0.y, 0.f);
            float e2 = fmaxf(bflo(a.y) * c0.z + h0.z, 0.f);
            float e3 = fmaxf(bfhi(a.y) * c0.w + h0.w, 0.f);
            float e4 = fmaxf(bflo(a.z) * c1.x + h1.x, 0.f);
            float e5 = fmaxf(bfhi(a.z) * c1.y + h1.y, 0.f);
            float e6 = fmaxf(bflo(a.w) * c1.z + h1.z, 0.f);
            float e7 = fmaxf(bfhi(a.w) * c1.w + h1.w, 0.f);
            o.x = pk(e0, e1); o.y = pk(e2, e3); o.z = pk(e4, e5); o.w = pk(e6, e7);
        }
        *reinterpret_cast<uint4*>((char*)sA + swz(r, gg * 16)) = o;
    }
#pragma unroll
    for (int j = 0; j < 8; j++) {
        int f = j * 256 + tid;
        int r = f >> 4, kb = f & 15;
        uint4 v = *reinterpret_cast<const uint4*>(WrT + r * H + kb * 8);
        *reinterpret_cast<uint4*>((char*)sB + swz(r, kb * 16)) = v;
    }
    __syncthreads();
#pragma unroll
    for (int kc = 0; kc < 4; kc++) {
        bh8 af = *reinterpret_cast<const bh8*>((char*)sA + swz(w * 16 + l15, kc * 64 + grp * 16));
#pragma unroll
        for (int nf = 0; nf < 8; nf++) {
            bh8 bv = *reinterpret_cast<const bh8*>((char*)sB + swz(nf * 16 + l15, kc * 64 + grp * 16));
            acc[nf] = __builtin_amdgcn_mfma_f32_16x16x32_bf16(af, bv, acc[nf], 0, 0, 0);
        }
    }

    // ---- epilogue: +bl, write bf16, BN2 stats ----
#pragma unroll
    for (int nf = 0; nf < 8; nf++) {
        int col = nf * 16 + l15;
        float bc = bl[col];
        float s = 0.f, q = 0.f;
#pragma unroll
        for (int j = 0; j < 4; j++) {
            int row = rb + w * 16 + grp * 4 + j;
            float u = acc[nf][j] + bc;
            if (row < n) {
                out[(size_t)row * H + col] = f2bf(u);
                s += u; q += u * u;
            }
        }
        s += __shfl_xor(s, 16, 64); s += __shfl_xor(s, 32, 64);
        q += __shfl_xor(q, 16, 64); q += __shfl_xor(q, 32, 64);
        if (grp == 0) { atomicAdd(&cs[col], s); atomicAdd(&css[col], q); }
    }
    __syncthreads();
    if (tid < 128) { atomicAdd(gsum + tid, cs[tid]); atomicAdd(gsumsq + tid, css[tid]); }
}

__global__ void k_bnparams(const float* __restrict__ gsum, const float* __restrict__ gsumsq,
                           const float* __restrict__ g, const float* __restrict__ b,
                           float* __restrict__ scale, float* __restrict__ shift, float inv_n)
{
    int c = threadIdx.x;
    float mu = gsum[c] * inv_n;
    float var = fmaxf(gsumsq[c] * inv_n - mu * mu, 0.f);
    float sc = g[c] * rsqrtf(var + BN_EPS);
    scale[c] = sc;
    shift[c] = b[c] - mu * sc;
}

// GCN dense part: xws_bf = bf16(dinv[row] * (relu(affine2(h2)) @ Wg)); h2 bf16 in
__global__ __launch_bounds__(320) void k_gcn(
    const u16* __restrict__ H2, const float* __restrict__ scale2, const float* __restrict__ shift2,
    const float* __restrict__ Wg, const float* __restrict__ dinv,
    u16* __restrict__ xwsb, int n)
{
    __shared__ float sW[H * OUTD];
    __shared__ float sA[32][H];
    const int tid = threadIdx.x;
#pragma unroll
    for (int j = 0; j < 4; j++) {
        int off = (tid + j * 320) * 4;
        *reinterpret_cast<float4*>(&sW[off]) = ld4(Wg + off);
    }
    const int rb = blockIdx.x * 32;
#pragma unroll
    for (int j = 0; j < 2; j++) {
        int li = tid + j * 320;
        if (li < 512) {
            int r = li >> 4, g = li & 15;
            int row = rb + r;
            float4 v0 = {0.f, 0.f, 0.f, 0.f}, v1 = {0.f, 0.f, 0.f, 0.f};
            if (row < n) {
                uint4 a = *reinterpret_cast<const uint4*>(H2 + (size_t)row * H + g * 8);
                float4 sc0 = ld4(scale2 + g * 8), sc1 = ld4(scale2 + g * 8 + 4);
                float4 sh0 = ld4(shift2 + g * 8), sh1 = ld4(shift2 + g * 8 + 4);
                v0.x = fmaxf(bflo(a.x) * sc0.x + sh0.x, 0.f);
                v0.y = fmaxf(bfhi(a.x) * sc0.y + sh0.y, 0.f);
                v0.z = fmaxf(bflo(a.y) * sc0.z + sh0.z, 0.f);
                v0.w = fmaxf(bfhi(a.y) * sc0.w + sh0.w, 0.f);
                v1.x = fmaxf(bflo(a.z) * sc1.x + sh1.x, 0.f);
                v1.y = fmaxf(bfhi(a.z) * sc1.y + sh1.y, 0.f);
                v1.z = fmaxf(bflo(a.w) * sc1.z + sh1.z, 0.f);
                v1.w = fmaxf(bfhi(a.w) * sc1.w + sh1.w, 0.f);
            }
            *reinterpret_cast<float4*>(&sA[r][g * 8]) = v0;
            *reinterpret_cast<float4*>(&sA[r][g * 8 + 4]) = v1;
        }
    }
    __syncthreads();
    const int c = tid % OUTD;
    const int rg = tid / OUTD;
    float acc[4] = {0.f, 0.f, 0.f, 0.f};
    for (int k = 0; k < H; k++) {
        float w = sW[k * OUTD + c];
#pragma unroll
        for (int i = 0; i < 4; i++) acc[i] += sA[rg + i * 8][k] * w;
    }
#pragma unroll
    for (int i = 0; i < 4; i++) {
        int row = rb + rg + i * 8;
        if (row < n) xwsb[(size_t)row * OUTD + c] = f2bf(dinv[row] * acc[i]);
    }
}

// GCN gather + self-loop + bias + log-softmax; xws bf16; 8-deep ILP
__global__ __launch_bounds__(256) void k_agg3(
    const u16* __restrict__ xwsb, const float* __restrict__ dinv,
    const int* __restrict__ csr, const int* __restrict__ cursor, const int* __restrict__ deg,
    const float* __restrict__ bias, float* __restrict__ outp, int n)
{
    int wid = (blockIdx.x * 256 + threadIdx.x) >> 6;
    int lane = threadIdx.x & 63;
    if (wid >= n) return;
    int end = cursor[wid];
    int start = end - deg[wid];
    bool act = lane < OUTD;
    int col = act ? lane : 0;
    float acc = 0.f;
    int i = start;
    for (; i + 8 <= end; i += 8) {
        int s0 = csr[i], s1 = csr[i + 1], s2 = csr[i + 2], s3 = csr[i + 3];
        int s4 = csr[i + 4], s5 = csr[i + 5], s6 = csr[i + 6], s7 = csr[i + 7];
        float a0 = bflo(xwsb[(size_t)s0 * OUTD + col]);
        float a1 = bflo(xwsb[(size_t)s1 * OUTD + col]);
        float a2 = bflo(xwsb[(size_t)s2 * OUTD + col]);
        float a3 = bflo(xwsb[(size_t)s3 * OUTD + col]);
        float a4 = bflo(xwsb[(size_t)s4 * OUTD + col]);
        float a5 = bflo(xwsb[(size_t)s5 * OUTD + col]);
        float a6 = bflo(xwsb[(size_t)s6 * OUTD + col]);
        float a7 = bflo(xwsb[(size_t)s7 * OUTD + col]);
        acc += ((a0 + a1) + (a2 + a3)) + ((a4 + a5) + (a6 + a7));
    }
    for (; i + 2 <= end; i += 2) {
        int s0 = csr[i], s1 = csr[i + 1];
        acc += bflo(xwsb[(size_t)s0 * OUTD + col]) + bflo(xwsb[(size_t)s1 * OUTD + col]);
    }
    for (; i < end; i++) {
        int s = csr[i];
        acc += bflo(xwsb[(size_t)s * OUTD + col]);
    }
    float di = dinv[wid];
    float v = di * (acc + bflo(xwsb[(size_t)wid * OUTD + col])) + bias[col];
    float m = act ? v : -INFINITY;
#pragma unroll
    for (int s = 1; s < 64; s <<= 1) m = fmaxf(m, __shfl_xor(m, s, 64));
    float ex = act ? expf(v - m) : 0.f;
    float sum = ex;
#pragma unroll
    for (int s = 1; s < 64; s <<= 1) sum += __shfl_xor(sum, s, 64);
    float l = logf(sum);
    if (act) outp[(size_t)wid * OUTD + lane] = v - m - l;
}

extern "C" void kernel_launch(void* const* d_in, const int* in_sizes, int n_in,
                              void* d_out, int out_size, void* d_ws, size_t ws_size,
                              hipStream_t stream)
{
    const float* x     = (const float*)d_in[0];
    const int*   ei    = (const int*)d_in[1];
    const float* w1    = (const float*)d_in[2];
    const float* b1    = (const float*)d_in[3];
    const float* w2    = (const float*)d_in[4];
    const float* b2    = (const float*)d_in[5];
    const float* bn1g  = (const float*)d_in[6];
    const float* bn1b  = (const float*)d_in[7];
    const float* wl    = (const float*)d_in[8];
    const float* bls   = (const float*)d_in[9];
    const float* wr    = (const float*)d_in[10];
    const float* bn2g  = (const float*)d_in[11];
    const float* bn2b  = (const float*)d_in[12];
    const float* wg    = (const float*)d_in[13];
    const float* bg    = (const float*)d_in[14];

    const int N = in_sizes[0] / H;
    const int E = in_sizes[1] / 2;
    const int* src = ei;
    const int* dst = ei + E;
    float* outp = (float*)d_out;

    // workspace (bf16-centric)
    u16* P0   = (u16*)d_ws;                      // N*H bf16
    u16* P1   = P0 + (size_t)N * H;              // N*H bf16
    u16* P2   = P1 + (size_t)N * H;              // N*H bf16 (holds xb, then h)
    u16* xwsb = P2 + (size_t)N * H;              // N*OUTD bf16
    float* dinv = (float*)(xwsb + (size_t)N * OUTD);
    float* st   = dinv + N;                      // 1024 floats
    int*  deg   = (int*)(st + 1024);
    int*  cursor= deg + N;
    int*  bsum  = cursor + N;
    int*  csr   = bsum + 1024;                   // E ints
    u16* wt1 = (u16*)(csr + E);
    u16* wt2 = wt1 + 16384;
    u16* wtl = wt2 + 16384;
    u16* wtr = wtl + 16384;
    float* sum1 = st,        *sumsq1 = st + 128;
    float* sum2 = st + 256,  *sumsq2 = st + 384;
    float* scale1 = st + 512, *shift1 = st + 640;
    float* scale2 = st + 768, *shift2 = st + 896;

    hipMemsetAsync(deg, 0, (size_t)N * sizeof(int), stream);
    hipMemsetAsync(st, 0, 1024 * sizeof(float), stream);

    const int eblk = (E + 255) / 256;
    const int nb = (N + 1023) / 1024;
    const int total8 = N * H / 8;

    k_xbf<<<(total8 + 255) / 256, 256, 0, stream>>>(x, P2, total8);   // xb in P2
    k_prep<<<256, 256, 0, stream>>>(w1, w2, wl, wr, wt1, wt2, wtl, wtr);
    k_hist<<<eblk, 256, 0, stream>>>(dst, deg, E);
    k_scan1<<<nb, 256, 0, stream>>>(deg, cursor, bsum, N);
    k_scan2<<<1, 256, 0, stream>>>(bsum, nb);
    k_scan3<<<(N + 255) / 256, 256, 0, stream>>>(cursor, bsum, deg, dinv, N);
    {
        const int q = (N + 3) / 4;
        k_fill_range<<<eblk, 256, 0, stream>>>(src, dst, cursor, csr, E, 0, q);
        k_fill_range<<<eblk, 256, 0, stream>>>(src, dst, cursor, csr, E, q, 2 * q);
        k_fill_range<<<eblk, 256, 0, stream>>>(src, dst, cursor, csr, E, 2 * q, 3 * q);
        k_fill_range<<<eblk, 256, 0, stream>>>(src, dst, cursor, csr, E, 3 * q, N);
    }

    const int gblocks = (N + 63) / 64;

    // ---- layer 1 (fused gather+GEMM1) ----
    k_agg1lin1<<<gblocks, 256, 0, stream>>>(P2, csr, cursor, deg, wt1, b1, P1, N);
    k_gemm_lin2norm<<<gblocks, 256, 0, stream>>>(P1, wt2, b2, P0, sum1, sumsq1, N);
    k_bnparams<<<1, 128, 0, stream>>>(sum1, sumsq1, bn1g, bn1b, scale1, shift1, 1.0f / N);

    // ---- layer 2 (fused gather+SAGE); h lives in P0 now ----
    k_agg2sage<<<gblocks, 256, 0, stream>>>(P0, csr, cursor, deg, scale1, shift1,
                                            wtl, wtr, bls, P1, sum2, sumsq2, N);
    k_bnparams<<<1, 128, 0, stream>>>(sum2, sumsq2, bn2g, bn2b, scale2, shift2, 1.0f / N);

    // ---- layer 3 ----
    k_gcn<<<(N + 31) / 32, 320, 0, stream>>>(P1, scale2, shift2, wg, dinv, xwsb, N);
    k_agg3<<<(N * 64 + 255) / 256, 256, 0, stream>>>(xwsb, dinv, csr, cursor, deg, bg, outp, N);
}

// Round 9
// 562.303 us; speedup vs baseline: 1.1163x; 1.1163x over previous
//
#include <hip/hip_runtime.h>
#include <math.h>

#define H 128
#define OUTD 40
#define BN_EPS 1e-5f
#define NEG_SLOPE 0.01f

typedef __attribute__((ext_vector_type(8))) short bh8;
typedef __attribute__((ext_vector_type(4))) float f4;
typedef unsigned short u16;

__device__ __forceinline__ float4 ld4(const float* p) {
    return *reinterpret_cast<const float4*>(p);
}
__device__ __forceinline__ u16 f2bf(float f) {
    unsigned int u = __float_as_uint(f);
    u += 0x7fffu + ((u >> 16) & 1u);          // RNE
    return (u16)(u >> 16);
}
__device__ __forceinline__ float bflo(unsigned d) { return __uint_as_float(d << 16); }
__device__ __forceinline__ float bfhi(unsigned d) { return __uint_as_float(d & 0xffff0000u); }
__device__ __forceinline__ unsigned pk(float a, float b) {
    return (unsigned)f2bf(a) | ((unsigned)f2bf(b) << 16);
}
// LDS XOR swizzle for 256B rows (bf16 x 128)
__device__ __forceinline__ int swz(int row, int byteInRow) {
    return row * 256 + (byteInRow ^ ((row & 7) << 4));
}

// ================= x -> bf16 =================
__global__ __launch_bounds__(256) void k_xbf(
    const float* __restrict__ x, u16* __restrict__ xb, int total8)
{
    int i = blockIdx.x * 256 + threadIdx.x;
    if (i >= total8) return;
    float4 a = ld4(x + (size_t)i * 8);
    float4 b = ld4(x + (size_t)i * 8 + 4);
    uint4 o;
    o.x = pk(a.x, a.y); o.y = pk(a.z, a.w);
    o.z = pk(b.x, b.y); o.w = pk(b.z, b.w);
    *reinterpret_cast<uint4*>(xb + (size_t)i * 8) = o;
}

// ================= weight prep: WT[c][k] = bf16(W[k][c]) =================
__global__ __launch_bounds__(256) void k_prep(
    const float* __restrict__ w1, const float* __restrict__ w2,
    const float* __restrict__ wl, const float* __restrict__ wr,
    u16* __restrict__ wt1, u16* __restrict__ wt2,
    u16* __restrict__ wtl, u16* __restrict__ wtr)
{
    int id = blockIdx.x * 256 + threadIdx.x;
    int sel = id >> 14;
    int o = id & 16383;
    int c = o >> 7, k = o & 127;
    const float* w = (sel == 0) ? w1 : (sel == 1) ? w2 : (sel == 2) ? wl : wr;
    u16* wt = (sel == 0) ? wt1 : (sel == 1) ? wt2 : (sel == 2) ? wtl : wtr;
    wt[o] = f2bf(w[k * H + c]);
}

// ================= CSR build =================
__global__ __launch_bounds__(256) void k_hist(
    const int* __restrict__ dst, int* __restrict__ deg, int E)
{
    int e = blockIdx.x * 256 + threadIdx.x;
    if (e < E) atomicAdd(&deg[dst[e]], 1);
}

__global__ __launch_bounds__(256) void k_scan1(
    const int* __restrict__ deg, int* __restrict__ cursor, int* __restrict__ bsum, int n)
{
    __shared__ int sums[256];
    const int tid = threadIdx.x;
    const int idx = blockIdx.x * 1024 + tid * 4;
    int4 v = {0, 0, 0, 0};
    if (idx + 3 < n) v = *reinterpret_cast<const int4*>(deg + idx);
    else {
        if (idx + 0 < n) v.x = deg[idx + 0];
        if (idx + 1 < n) v.y = deg[idx + 1];
        if (idx + 2 < n) v.z = deg[idx + 2];
        if (idx + 3 < n) v.w = deg[idx + 3];
    }
    int t = v.x + v.y + v.z + v.w;
    sums[tid] = t;
    __syncthreads();
    for (int off = 1; off < 256; off <<= 1) {
        int other = (tid >= off) ? sums[tid - off] : 0;
        __syncthreads();
        sums[tid] += other;
        __syncthreads();
    }
    int incl = sums[tid];
    int excl = incl - t;
    if (tid == 255) bsum[blockIdx.x] = incl;
    int c0 = excl, c1 = c0 + v.x, c2 = c1 + v.y, c3 = c2 + v.z;
    if (idx + 3 < n) {
        int4 o = {c0, c1, c2, c3};
        *reinterpret_cast<int4*>(cursor + idx) = o;
    } else {
        if (idx + 0 < n) cursor[idx + 0] = c0;
        if (idx + 1 < n) cursor[idx + 1] = c1;
        if (idx + 2 < n) cursor[idx + 2] = c2;
        if (idx + 3 < n) cursor[idx + 3] = c3;
    }
}

__global__ void k_scan2(int* __restrict__ bsum, int nb)
{
    __shared__ int s[1024];
    const int tid = threadIdx.x;
    for (int i = tid; i < nb; i += blockDim.x) s[i] = bsum[i];
    __syncthreads();
    if (tid == 0) {
        int acc = 0;
        for (int i = 0; i < nb; i++) { int t = s[i]; s[i] = acc; acc += t; }
    }
    __syncthreads();
    for (int i = tid; i < nb; i += blockDim.x) bsum[i] = s[i];
}

// scan3 + dinv fused
__global__ __launch_bounds__(256) void k_scan3(
    int* __restrict__ cursor, const int* __restrict__ bsum,
    const int* __restrict__ deg, float* __restrict__ dinv, int n)
{
    int i = blockIdx.x * 256 + threadIdx.x;
    if (i < n) {
        cursor[i] += bsum[i >> 10];
        dinv[i] = rsqrtf((float)deg[i] + 1.0f);
    }
}

// ranged fill: csr write window (~1.6MB) stays L2-resident per pass
__global__ __launch_bounds__(256) void k_fill_range(
    const int* __restrict__ src, const int* __restrict__ dst,
    int* __restrict__ cursor, int* __restrict__ csr, int E, int lo, int hi)
{
    int e = blockIdx.x * 256 + threadIdx.x;
    if (e >= E) return;
    int d = dst[e];
    if (d < lo || d >= hi) return;
    int pos = atomicAdd(&cursor[d], 1);
    csr[pos] = src[e];
}

// ================= gather aggregations (bf16 features) =================
// 4 rows per wave, 16 lanes per row, 16B (8 bf16) per lane; 4-deep ILP
__global__ __launch_bounds__(256) void k_agg1(
    const u16* __restrict__ xb, const int* __restrict__ csr,
    const int* __restrict__ cursor, const int* __restrict__ deg,
    u16* __restrict__ out, int n)
{
    int wave = (blockIdx.x * 256 + threadIdx.x) >> 6;
    int lane = threadIdx.x & 63;
    int row = wave * 4 + (lane >> 4);
    if (row >= n) return;
    int g = lane & 15;
    int end = cursor[row];
    int start = end - deg[row];
    float acc[8] = {0.f, 0.f, 0.f, 0.f, 0.f, 0.f, 0.f, 0.f};
    int i = start;
    for (; i + 4 <= end; i += 4) {
        int s0 = csr[i], s1 = csr[i + 1], s2 = csr[i + 2], s3 = csr[i + 3];
        uint4 a = *reinterpret_cast<const uint4*>(xb + (size_t)s0 * H + g * 8);
        uint4 b = *reinterpret_cast<const uint4*>(xb + (size_t)s1 * H + g * 8);
        uint4 c = *reinterpret_cast<const uint4*>(xb + (size_t)s2 * H + g * 8);
        uint4 d = *reinterpret_cast<const uint4*>(xb + (size_t)s3 * H + g * 8);
        acc[0] += (bflo(a.x) + bflo(b.x)) + (bflo(c.x) + bflo(d.x));
        acc[1] += (bfhi(a.x) + bfhi(b.x)) + (bfhi(c.x) + bfhi(d.x));
        acc[2] += (bflo(a.y) + bflo(b.y)) + (bflo(c.y) + bflo(d.y));
        acc[3] += (bfhi(a.y) + bfhi(b.y)) + (bfhi(c.y) + bfhi(d.y));
        acc[4] += (bflo(a.z) + bflo(b.z)) + (bflo(c.z) + bflo(d.z));
        acc[5] += (bfhi(a.z) + bfhi(b.z)) + (bfhi(c.z) + bfhi(d.z));
        acc[6] += (bflo(a.w) + bflo(b.w)) + (bflo(c.w) + bflo(d.w));
        acc[7] += (bfhi(a.w) + bfhi(b.w)) + (bfhi(c.w) + bfhi(d.w));
    }
    for (; i < end; i++) {
        int s = csr[i];
        uint4 a = *reinterpret_cast<const uint4*>(xb + (size_t)s * H + g * 8);
        acc[0] += bflo(a.x); acc[1] += bfhi(a.x);
        acc[2] += bflo(a.y); acc[3] += bfhi(a.y);
        acc[4] += bflo(a.z); acc[5] += bfhi(a.z);
        acc[6] += bflo(a.w); acc[7] += bfhi(a.w);
    }
    uint4 o;
    o.x = pk(acc[0], acc[1]); o.y = pk(acc[2], acc[3]);
    o.z = pk(acc[4], acc[5]); o.w = pk(acc[6], acc[7]);
    *reinterpret_cast<uint4*>(out + (size_t)row * H + g * 8) = o;
}

// act1h = bf16(relu(affine1(h))), elementwise
__global__ __launch_bounds__(256) void k_act1(
    const u16* __restrict__ hb, const float* __restrict__ scale, const float* __restrict__ shift,
    u16* __restrict__ out, int total8)
{
    int i = blockIdx.x * 256 + threadIdx.x;
    if (i >= total8) return;
    int g = i & 15;
    uint4 a = *reinterpret_cast<const uint4*>(hb + (size_t)i * 8);
    float4 sc0 = ld4(scale + g * 8), sc1 = ld4(scale + g * 8 + 4);
    float4 sh0 = ld4(shift + g * 8), sh1 = ld4(shift + g * 8 + 4);
    float e0 = fmaxf(bflo(a.x) * sc0.x + sh0.x, 0.f);
    float e1 = fmaxf(bfhi(a.x) * sc0.y + sh0.y, 0.f);
    float e2 = fmaxf(bflo(a.y) * sc0.z + sh0.z, 0.f);
    float e3 = fmaxf(bfhi(a.y) * sc0.w + sh0.w, 0.f);
    float e4 = fmaxf(bflo(a.z) * sc1.x + sh1.x, 0.f);
    float e5 = fmaxf(bfhi(a.z) * sc1.y + sh1.y, 0.f);
    float e6 = fmaxf(bflo(a.w) * sc1.z + sh1.z, 0.f);
    float e7 = fmaxf(bfhi(a.w) * sc1.w + sh1.w, 0.f);
    uint4 o;
    o.x = pk(e0, e1); o.y = pk(e2, e3); o.z = pk(e4, e5); o.w = pk(e6, e7);
    *reinterpret_cast<uint4*>(out + (size_t)i * 8) = o;
}

// mean gather over precomputed act1h (pure sum, like agg1) + /deg
__global__ __launch_bounds__(256) void k_agg2(
    const u16* __restrict__ ab, const int* __restrict__ csr,
    const int* __restrict__ cursor, const int* __restrict__ deg,
    u16* __restrict__ out, int n)
{
    int wave = (blockIdx.x * 256 + threadIdx.x) >> 6;
    int lane = threadIdx.x & 63;
    int row = wave * 4 + (lane >> 4);
    if (row >= n) return;
    int g = lane & 15;
    int end = cursor[row];
    int dg = deg[row];
    int start = end - dg;
    float acc[8] = {0.f, 0.f, 0.f, 0.f, 0.f, 0.f, 0.f, 0.f};
    int i = start;
    for (; i + 4 <= end; i += 4) {
        int s0 = csr[i], s1 = csr[i + 1], s2 = csr[i + 2], s3 = csr[i + 3];
        uint4 a = *reinterpret_cast<const uint4*>(ab + (size_t)s0 * H + g * 8);
        uint4 b = *reinterpret_cast<const uint4*>(ab + (size_t)s1 * H + g * 8);
        uint4 c = *reinterpret_cast<const uint4*>(ab + (size_t)s2 * H + g * 8);
        uint4 d = *reinterpret_cast<const uint4*>(ab + (size_t)s3 * H + g * 8);
        acc[0] += (bflo(a.x) + bflo(b.x)) + (bflo(c.x) + bflo(d.x));
        acc[1] += (bfhi(a.x) + bfhi(b.x)) + (bfhi(c.x) + bfhi(d.x));
        acc[2] += (bflo(a.y) + bflo(b.y)) + (bflo(c.y) + bflo(d.y));
        acc[3] += (bfhi(a.y) + bfhi(b.y)) + (bfhi(c.y) + bfhi(d.y));
        acc[4] += (bflo(a.z) + bflo(b.z)) + (bflo(c.z) + bflo(d.z));
        acc[5] += (bfhi(a.z) + bfhi(b.z)) + (bfhi(c.z) + bfhi(d.z));
        acc[6] += (bflo(a.w) + bflo(b.w)) + (bflo(c.w) + bflo(d.w));
        acc[7] += (bfhi(a.w) + bfhi(b.w)) + (bfhi(c.w) + bfhi(d.w));
    }
    for (; i < end; i++) {
        int s = csr[i];
        uint4 a = *reinterpret_cast<const uint4*>(ab + (size_t)s * H + g * 8);
        acc[0] += bflo(a.x); acc[1] += bfhi(a.x);
        acc[2] += bflo(a.y); acc[3] += bfhi(a.y);
        acc[4] += bflo(a.z); acc[5] += bfhi(a.z);
        acc[6] += bflo(a.w); acc[7] += bfhi(a.w);
    }
    float idv = 1.0f / fmaxf((float)dg, 1.0f);
    uint4 o;
    o.x = pk(acc[0] * idv, acc[1] * idv); o.y = pk(acc[2] * idv, acc[3] * idv);
    o.z = pk(acc[4] * idv, acc[5] * idv); o.w = pk(acc[6] * idv, acc[7] * idv);
    *reinterpret_cast<uint4*>(out + (size_t)row * H + g * 8) = o;
}

// GCN gather + self-loop + bias + log-softmax; xws bf16; 8-deep ILP
__global__ __launch_bounds__(256) void k_agg3(
    const u16* __restrict__ xwsb, const float* __restrict__ dinv,
    const int* __restrict__ csr, const int* __restrict__ cursor, const int* __restrict__ deg,
    const float* __restrict__ bias, float* __restrict__ outp, int n)
{
    int wid = (blockIdx.x * 256 + threadIdx.x) >> 6;
    int lane = threadIdx.x & 63;
    if (wid >= n) return;
    int end = cursor[wid];
    int start = end - deg[wid];
    bool act = lane < OUTD;
    int col = act ? lane : 0;
    float acc = 0.f;
    int i = start;
    for (; i + 8 <= end; i += 8) {
        int s0 = csr[i], s1 = csr[i + 1], s2 = csr[i + 2], s3 = csr[i + 3];
        int s4 = csr[i + 4], s5 = csr[i + 5], s6 = csr[i + 6], s7 = csr[i + 7];
        float a0 = bflo(xwsb[(size_t)s0 * OUTD + col]);
        float a1 = bflo(xwsb[(size_t)s1 * OUTD + col]);
        float a2 = bflo(xwsb[(size_t)s2 * OUTD + col]);
        float a3 = bflo(xwsb[(size_t)s3 * OUTD + col]);
        float a4 = bflo(xwsb[(size_t)s4 * OUTD + col]);
        float a5 = bflo(xwsb[(size_t)s5 * OUTD + col]);
        float a6 = bflo(xwsb[(size_t)s6 * OUTD + col]);
        float a7 = bflo(xwsb[(size_t)s7 * OUTD + col]);
        acc += ((a0 + a1) + (a2 + a3)) + ((a4 + a5) + (a6 + a7));
    }
    for (; i + 2 <= end; i += 2) {
        int s0 = csr[i], s1 = csr[i + 1];
        acc += bflo(xwsb[(size_t)s0 * OUTD + col]) + bflo(xwsb[(size_t)s1 * OUTD + col]);
    }
    for (; i < end; i++) {
        int s = csr[i];
        acc += bflo(xwsb[(size_t)s * OUTD + col]);
    }
    float di = dinv[wid];
    float v = di * (acc + bflo(xwsb[(size_t)wid * OUTD + col])) + bias[col];
    float m = act ? v : -INFINITY;
#pragma unroll
    for (int s = 1; s < 64; s <<= 1) m = fmaxf(m, __shfl_xor(m, s, 64));
    float ex = act ? expf(v - m) : 0.f;
    float sum = ex;
#pragma unroll
    for (int s = 1; s < 64; s <<= 1) sum += __shfl_xor(sum, s, 64);
    float l = logf(sum);
    if (act) outp[(size_t)wid * OUTD + lane] = v - m - l;
}

// ================= MFMA dense layers =================
// GEMM1: out = bf16(leaky_relu(A @ W1 + b1)); A bf16
__global__ __launch_bounds__(256) void k_gemm_lin1(
    const u16* __restrict__ A, const u16* __restrict__ WT,
    const float* __restrict__ bias, u16* __restrict__ out, int n)
{
    __shared__ u16 sA[64 * 128];
    __shared__ u16 sB[128 * 128];
    const int tid = threadIdx.x;
    const int rb = blockIdx.x * 64;
#pragma unroll
    for (int j = 0; j < 4; j++) {
        int f = j * 256 + tid;
        int r = f >> 4, g = f & 15;
        int row = rb + r;
        uint4 v = {0, 0, 0, 0};
        if (row < n) v = *reinterpret_cast<const uint4*>(A + (size_t)row * H + g * 8);
        *reinterpret_cast<uint4*>((char*)sA + swz(r, g * 16)) = v;
    }
#pragma unroll
    for (int j = 0; j < 8; j++) {
        int f = j * 256 + tid;
        int r = f >> 4, kb = f & 15;
        uint4 v = *reinterpret_cast<const uint4*>(WT + r * H + kb * 8);
        *reinterpret_cast<uint4*>((char*)sB + swz(r, kb * 16)) = v;
    }
    __syncthreads();
    const int w = tid >> 6, l15 = tid & 15, grp = (tid & 63) >> 4;
    f4 acc[8] = {};
#pragma unroll
    for (int kc = 0; kc < 4; kc++) {
        bh8 af = *reinterpret_cast<const bh8*>((char*)sA + swz(w * 16 + l15, kc * 64 + grp * 16));
#pragma unroll
        for (int nf = 0; nf < 8; nf++) {
            bh8 bv = *reinterpret_cast<const bh8*>((char*)sB + swz(nf * 16 + l15, kc * 64 + grp * 16));
            acc[nf] = __builtin_amdgcn_mfma_f32_16x16x32_bf16(af, bv, acc[nf], 0, 0, 0);
        }
    }
#pragma unroll
    for (int nf = 0; nf < 8; nf++) {
        int col = nf * 16 + l15;
        float bc = bias[col];
#pragma unroll
        for (int j = 0; j < 4; j++) {
            int row = rb + w * 16 + grp * 4 + j;
            if (row < n) {
                float u = acc[nf][j] + bc;
                u = u > 0.f ? u : NEG_SLOPE * u;
                out[(size_t)row * H + col] = f2bf(u);
            }
        }
    }
}

// GEMM2: u = A @ W2 + b2; L2-normalize rows; write bf16 h; BN1 stats
__global__ __launch_bounds__(256) void k_gemm_lin2norm(
    const u16* __restrict__ A, const u16* __restrict__ WT,
    const float* __restrict__ bias, u16* __restrict__ out,
    float* __restrict__ gsum, float* __restrict__ gsumsq, int n)
{
    __shared__ u16 sA[64 * 128];
    __shared__ u16 sB[128 * 128];
    __shared__ float cs[128], css[128];
    const int tid = threadIdx.x;
    const int rb = blockIdx.x * 64;
    if (tid < 128) { cs[tid] = 0.f; css[tid] = 0.f; }
#pragma unroll
    for (int j = 0; j < 4; j++) {
        int f = j * 256 + tid;
        int r = f >> 4, g = f & 15;
        int row = rb + r;
        uint4 v = {0, 0, 0, 0};
        if (row < n) v = *reinterpret_cast<const uint4*>(A + (size_t)row * H + g * 8);
        *reinterpret_cast<uint4*>((char*)sA + swz(r, g * 16)) = v;
    }
#pragma unroll
    for (int j = 0; j < 8; j++) {
        int f = j * 256 + tid;
        int r = f >> 4, kb = f & 15;
        uint4 v = *reinterpret_cast<const uint4*>(WT + r * H + kb * 8);
        *reinterpret_cast<uint4*>((char*)sB + swz(r, kb * 16)) = v;
    }
    __syncthreads();
    const int w = tid >> 6, l15 = tid & 15, grp = (tid & 63) >> 4;
    f4 acc[8] = {};
#pragma unroll
    for (int kc = 0; kc < 4; kc++) {
        bh8 af = *reinterpret_cast<const bh8*>((char*)sA + swz(w * 16 + l15, kc * 64 + grp * 16));
#pragma unroll
        for (int nf = 0; nf < 8; nf++) {
            bh8 bv = *reinterpret_cast<const bh8*>((char*)sB + swz(nf * 16 + l15, kc * 64 + grp * 16));
            acc[nf] = __builtin_amdgcn_mfma_f32_16x16x32_bf16(af, bv, acc[nf], 0, 0, 0);
        }
    }
#pragma unroll
    for (int nf = 0; nf < 8; nf++) {
        float bc = bias[nf * 16 + l15];
#pragma unroll
        for (int j = 0; j < 4; j++) acc[nf][j] += bc;
    }
    float inv[4];
#pragma unroll
    for (int j = 0; j < 4; j++) {
        float ss = 0.f;
#pragma unroll
        for (int nf = 0; nf < 8; nf++) ss += acc[nf][j] * acc[nf][j];
        ss += __shfl_xor(ss, 1, 64); ss += __shfl_xor(ss, 2, 64);
        ss += __shfl_xor(ss, 4, 64); ss += __shfl_xor(ss, 8, 64);
        inv[j] = 1.0f / fmaxf(sqrtf(ss), 1e-12f);
    }
#pragma unroll
    for (int nf = 0; nf < 8; nf++) {
        int col = nf * 16 + l15;
        float s = 0.f, q = 0.f;
#pragma unroll
        for (int j = 0; j < 4; j++) {
            int row = rb + w * 16 + grp * 4 + j;
            float u = acc[nf][j] * inv[j];
            if (row < n) {
                out[(size_t)row * H + col] = f2bf(u);
                s += u; q += u * u;
            }
        }
        s += __shfl_xor(s, 16, 64); s += __shfl_xor(s, 32, 64);
        q += __shfl_xor(q, 16, 64); q += __shfl_xor(q, 32, 64);
        if (grp == 0) { atomicAdd(&cs[col], s); atomicAdd(&css[col], q); }
    }
    __syncthreads();
    if (tid < 128) { atomicAdd(gsum + tid, cs[tid]); atomicAdd(gsumsq + tid, css[tid]); }
}

// SAGE: v = meanagg @ Wl + bl + act1h @ Wr; h2 bf16 out; BN2 stats
__global__ __launch_bounds__(256) void k_gemm_sage(
    const u16* __restrict__ Am, const u16* __restrict__ Ab,
    const u16* __restrict__ WlT, const u16* __restrict__ WrT,
    const float* __restrict__ bl, u16* __restrict__ out,
    float* __restrict__ gsum, float* __restrict__ gsumsq, int n)
{
    __shared__ u16 sA[64 * 128];
    __shared__ u16 sB[128 * 128];
    __shared__ float cs[128], css[128];
    const int tid = threadIdx.x;
    const int rb = blockIdx.x * 64;
    if (tid < 128) { cs[tid] = 0.f; css[tid] = 0.f; }
    const int w = tid >> 6, l15 = tid & 15, grp = (tid & 63) >> 4;
    f4 acc[8] = {};

    // ---- pass 1: meanagg @ Wl ----
#pragma unroll
    for (int j = 0; j < 4; j++) {
        int f = j * 256 + tid;
        int r = f >> 4, g = f & 15;
        int row = rb + r;
        uint4 v = {0, 0, 0, 0};
        if (row < n) v = *reinterpret_cast<const uint4*>(Am + (size_t)row * H + g * 8);
        *reinterpret_cast<uint4*>((char*)sA + swz(r, g * 16)) = v;
    }
#pragma unroll
    for (int j = 0; j < 8; j++) {
        int f = j * 256 + tid;
        int r = f >> 4, kb = f & 15;
        uint4 v = *reinterpret_cast<const uint4*>(WlT + r * H + kb * 8);
        *reinterpret_cast<uint4*>((char*)sB + swz(r, kb * 16)) = v;
    }
    __syncthreads();
#pragma unroll
    for (int kc = 0; kc < 4; kc++) {
        bh8 af = *reinterpret_cast<const bh8*>((char*)sA + swz(w * 16 + l15, kc * 64 + grp * 16));
#pragma unroll
        for (int nf = 0; nf < 8; nf++) {
            bh8 bv = *reinterpret_cast<const bh8*>((char*)sB + swz(nf * 16 + l15, kc * 64 + grp * 16));
            acc[nf] = __builtin_amdgcn_mfma_f32_16x16x32_bf16(af, bv, acc[nf], 0, 0, 0);
        }
    }
    __syncthreads();

    // ---- pass 2: act1h @ Wr (plain copy staging) ----
#pragma unroll
    for (int j = 0; j < 4; j++) {
        int f = j * 256 + tid;
        int r = f >> 4, g = f & 15;
        int row = rb + r;
        uint4 v = {0, 0, 0, 0};
        if (row < n) v = *reinterpret_cast<const uint4*>(Ab + (size_t)row * H + g * 8);
        *reinterpret_cast<uint4*>((char*)sA + swz(r, g * 16)) = v;
    }
#pragma unroll
    for (int j = 0; j < 8; j++) {
        int f = j * 256 + tid;
        int r = f >> 4, kb = f & 15;
        uint4 v = *reinterpret_cast<const uint4*>(WrT + r * H + kb * 8);
        *reinterpret_cast<uint4*>((char*)sB + swz(r, kb * 16)) = v;
    }
    __syncthreads();
#pragma unroll
    for (int kc = 0; kc < 4; kc++) {
        bh8 af = *reinterpret_cast<const bh8*>((char*)sA + swz(w * 16 + l15, kc * 64 + grp * 16));
#pragma unroll
        for (int nf = 0; nf < 8; nf++) {
            bh8 bv = *reinterpret_cast<const bh8*>((char*)sB + swz(nf * 16 + l15, kc * 64 + grp * 16));
            acc[nf] = __builtin_amdgcn_mfma_f32_16x16x32_bf16(af, bv, acc[nf], 0, 0, 0);
        }
    }

    // ---- epilogue ----
#pragma unroll
    for (int nf = 0; nf < 8; nf++) {
        int col = nf * 16 + l15;
        float bc = bl[col];
        float s = 0.f, q = 0.f;
#pragma unroll
        for (int j = 0; j < 4; j++) {
            int row = rb + w * 16 + grp * 4 + j;
            float u = acc[nf][j] + bc;
            if (row < n) {
                out[(size_t)row * H + col] = f2bf(u);
                s += u; q += u * u;
            }
        }
        s += __shfl_xor(s, 16, 64); s += __shfl_xor(s, 32, 64);
        q += __shfl_xor(q, 16, 64); q += __shfl_xor(q, 32, 64);
        if (grp == 0) { atomicAdd(&cs[col], s); atomicAdd(&css[col], q); }
    }
    __syncthreads();
    if (tid < 128) { atomicAdd(gsum + tid, cs[tid]); atomicAdd(gsumsq + tid, css[tid]); }
}

__global__ void k_bnparams(const float* __restrict__ gsum, const float* __restrict__ gsumsq,
                           const float* __restrict__ g, const float* __restrict__ b,
                           float* __restrict__ scale, float* __restrict__ shift, float inv_n)
{
    int c = threadIdx.x;
    float mu = gsum[c] * inv_n;
    float var = fmaxf(gsumsq[c] * inv_n - mu * mu, 0.f);
    float sc = g[c] * rsqrtf(var + BN_EPS);
    scale[c] = sc;
    shift[c] = b[c] - mu * sc;
}

// GCN dense part: xws_bf = bf16(dinv[row] * (relu(affine2(h2)) @ Wg)); h2 bf16 in
__global__ __launch_bounds__(320) void k_gcn(
    const u16* __restrict__ H2, const float* __restrict__ scale2, const float* __restrict__ shift2,
    const float* __restrict__ Wg, const float* __restrict__ dinv,
    u16* __restrict__ xwsb, int n)
{
    __shared__ float sW[H * OUTD];
    __shared__ float sA[32][H];
    const int tid = threadIdx.x;
#pragma unroll
    for (int j = 0; j < 4; j++) {
        int off = (tid + j * 320) * 4;
        *reinterpret_cast<float4*>(&sW[off]) = ld4(Wg + off);
    }
    const int rb = blockIdx.x * 32;
#pragma unroll
    for (int j = 0; j < 2; j++) {
        int li = tid + j * 320;
        if (li < 512) {
            int r = li >> 4, g = li & 15;
            int row = rb + r;
            float4 v0 = {0.f, 0.f, 0.f, 0.f}, v1 = {0.f, 0.f, 0.f, 0.f};
            if (row < n) {
                uint4 a = *reinterpret_cast<const uint4*>(H2 + (size_t)row * H + g * 8);
                float4 sc0 = ld4(scale2 + g * 8), sc1 = ld4(scale2 + g * 8 + 4);
                float4 sh0 = ld4(shift2 + g * 8), sh1 = ld4(shift2 + g * 8 + 4);
                v0.x = fmaxf(bflo(a.x) * sc0.x + sh0.x, 0.f);
                v0.y = fmaxf(bfhi(a.x) * sc0.y + sh0.y, 0.f);
                v0.z = fmaxf(bflo(a.y) * sc0.z + sh0.z, 0.f);
                v0.w = fmaxf(bfhi(a.y) * sc0.w + sh0.w, 0.f);
                v1.x = fmaxf(bflo(a.z) * sc1.x + sh1.x, 0.f);
                v1.y = fmaxf(bfhi(a.z) * sc1.y + sh1.y, 0.f);
                v1.z = fmaxf(bflo(a.w) * sc1.z + sh1.z, 0.f);
                v1.w = fmaxf(bfhi(a.w) * sc1.w + sh1.w, 0.f);
            }
            *reinterpret_cast<float4*>(&sA[r][g * 8]) = v0;
            *reinterpret_cast<float4*>(&sA[r][g * 8 + 4]) = v1;
        }
    }
    __syncthreads();
    const int c = tid % OUTD;
    const int rg = tid / OUTD;
    float acc[4] = {0.f, 0.f, 0.f, 0.f};
    for (int k = 0; k < H; k++) {
        float w = sW[k * OUTD + c];
#pragma unroll
        for (int i = 0; i < 4; i++) acc[i] += sA[rg + i * 8][k] * w;
    }
#pragma unroll
    for (int i = 0; i < 4; i++) {
        int row = rb + rg + i * 8;
        if (row < n) xwsb[(size_t)row * OUTD + c] = f2bf(dinv[row] * acc[i]);
    }
}

extern "C" void kernel_launch(void* const* d_in, const int* in_sizes, int n_in,
                              void* d_out, int out_size, void* d_ws, size_t ws_size,
                              hipStream_t stream)
{
    const float* x     = (const float*)d_in[0];
    const int*   ei    = (const int*)d_in[1];
    const float* w1    = (const float*)d_in[2];
    const float* b1    = (const float*)d_in[3];
    const float* w2    = (const float*)d_in[4];
    const float* b2    = (const float*)d_in[5];
    const float* bn1g  = (const float*)d_in[6];
    const float* bn1b  = (const float*)d_in[7];
    const float* wl    = (const float*)d_in[8];
    const float* bls   = (const float*)d_in[9];
    const float* wr    = (const float*)d_in[10];
    const float* bn2g  = (const float*)d_in[11];
    const float* bn2b  = (const float*)d_in[12];
    const float* wg    = (const float*)d_in[13];
    const float* bg    = (const float*)d_in[14];

    const int N = in_sizes[0] / H;
    const int E = in_sizes[1] / 2;
    const int* src = ei;
    const int* dst = ei + E;
    float* outp = (float*)d_out;

    // workspace (bf16-centric)
    u16* P0   = (u16*)d_ws;                      // N*H bf16
    u16* P1   = P0 + (size_t)N * H;              // N*H bf16
    u16* P2   = P1 + (size_t)N * H;              // N*H bf16
    u16* xwsb = P2 + (size_t)N * H;              // N*OUTD bf16
    float* dinv = (float*)(xwsb + (size_t)N * OUTD);
    float* st   = dinv + N;                      // 1024 floats
    int*  deg   = (int*)(st + 1024);
    int*  cursor= deg + N;
    int*  bsum  = cursor + N;
    int*  csr   = bsum + 1024;                   // E ints
    u16* wt1 = (u16*)(csr + E);
    u16* wt2 = wt1 + 16384;
    u16* wtl = wt2 + 16384;
    u16* wtr = wtl + 16384;
    float* sum1 = st,        *sumsq1 = st + 128;
    float* sum2 = st + 256,  *sumsq2 = st + 384;
    float* scale1 = st + 512, *shift1 = st + 640;
    float* scale2 = st + 768, *shift2 = st + 896;

    hipMemsetAsync(deg, 0, (size_t)N * sizeof(int), stream);
    hipMemsetAsync(st, 0, 1024 * sizeof(float), stream);

    const int eblk = (E + 255) / 256;
    const int nb = (N + 1023) / 1024;
    const int total8 = N * H / 8;

    k_xbf<<<(total8 + 255) / 256, 256, 0, stream>>>(x, P2, total8);   // xb in P2
    k_prep<<<256, 256, 0, stream>>>(w1, w2, wl, wr, wt1, wt2, wtl, wtr);
    k_hist<<<eblk, 256, 0, stream>>>(dst, deg, E);
    k_scan1<<<nb, 256, 0, stream>>>(deg, cursor, bsum, N);
    k_scan2<<<1, 256, 0, stream>>>(bsum, nb);
    k_scan3<<<(N + 255) / 256, 256, 0, stream>>>(cursor, bsum, deg, dinv, N);
    {
        const int q = (N + 3) / 4;
        k_fill_range<<<eblk, 256, 0, stream>>>(src, dst, cursor, csr, E, 0, q);
        k_fill_range<<<eblk, 256, 0, stream>>>(src, dst, cursor, csr, E, q, 2 * q);
        k_fill_range<<<eblk, 256, 0, stream>>>(src, dst, cursor, csr, E, 2 * q, 3 * q);
        k_fill_range<<<eblk, 256, 0, stream>>>(src, dst, cursor, csr, E, 3 * q, N);
    }

    const int aggblk4 = (N + 15) / 16;           // 4 rows/wave, 4 waves/block
    const int gblocks = (N + 63) / 64;

    // ---- layer 1 ----
    k_agg1<<<aggblk4, 256, 0, stream>>>(P2, csr, cursor, deg, P0, N);       // xb->neigh
    k_gemm_lin1<<<gblocks, 256, 0, stream>>>(P0, wt1, b1, P1, N);           // ->inter
    k_gemm_lin2norm<<<gblocks, 256, 0, stream>>>(P1, wt2, b2, P2, sum1, sumsq1, N);  // ->h
    k_bnparams<<<1, 128, 0, stream>>>(sum1, sumsq1, bn1g, bn1b, scale1, shift1, 1.0f / N);

    // ---- layer 2 ----
    k_act1<<<(total8 + 255) / 256, 256, 0, stream>>>(P2, scale1, shift1, P0, total8); // h->act1h
    k_agg2<<<aggblk4, 256, 0, stream>>>(P0, csr, cursor, deg, P1, N);       // act1h->meanagg
    k_gemm_sage<<<gblocks, 256, 0, stream>>>(P1, P0, wtl, wtr, bls, P1, sum2, sumsq2, N); // ->h2
    k_bnparams<<<1, 128, 0, stream>>>(sum2, sumsq2, bn2g, bn2b, scale2, shift2, 1.0f / N);

    // ---- layer 3 ----
    k_gcn<<<(N + 31) / 32, 320, 0, stream>>>(P1, scale2, shift2, wg, dinv, xwsb, N);
    k_agg3<<<(N * 64 + 255) / 256, 256, 0, stream>>>(xwsb, dinv, csr, cursor, deg, bg, outp, N);
}